// Round 10
// baseline (775.900 us; speedup 1.0000x reference)
//
#include <hip/hip_runtime.h>
#include <hip/hip_bf16.h>

// ExpertMLPsV2: T=4096, H=2048, I=4096, E=8, TOPK=2.
// cvt/route -> tcvt weights bf16 (N,K) -> fused gate+up GEMM (ring-4 slice
// pipeline) -> tcvt wd -> down GEMM (ring-4) -> combine.
// Ring-4: BK-slice=32, 4 LDS slots, stage slice s+3 while computing slice s.
// ONE barrier per slice: [stage issue][12 ds_reads][32 MFMA][vmcnt(8)][barrier].
// Intra-slice barriers removed (r8 post-mortem: they were pure align overhead;
// slot validity is guaranteed by the previous boundary, MFMA deps enforce lgkm).
// LDS: linear dest for DMA; 16B k-slot XOR-swizzled (s^((row>>1)&3)) via
// pre-swizzled global source; read-side XOR folds into per-lane constant fo.
// (identical to round-9 submission; that round died to an infra failure pre-run)

constexpr int kT   = 4096;
constexpr int kH   = 2048;
constexpr int kI   = 4096;
constexpr int kE   = 8;
constexpr int kCap = 4096;
constexpr int kRowsCap = 10240;

typedef __attribute__((ext_vector_type(8))) short bf16x8;
typedef __attribute__((ext_vector_type(4))) float f32x4;

// ---------------- workspace layout ----------------
constexpr size_t HSB_OFF  = 0;                                      // hs bf16 16 MiB
constexpr size_t HBUF_OFF = 16777216;                               // h bf16 rowsCap x kI (80 MiB)
constexpr size_t RA_OFF   = HBUF_OFF + (size_t)kRowsCap * kI * 2;   // wgT -> wdT (128 MiB)
constexpr size_t RB_OFF   = RA_OFF + (size_t)kE * kH * kI * 2;      // wuT -> obuf (128 MiB)
constexpr size_t CNT_OFF  = RB_OFF + (size_t)kE * kH * kI * 2;
constexpr size_t OFF_OFF  = CNT_OFF + 256;
constexpr size_t LTOK_OFF = OFF_OFF + 256;
constexpr size_t LW_OFF   = LTOK_OFF + (size_t)kE * kCap * 4;
constexpr size_t POS_OFF  = LW_OFF + (size_t)kE * kCap * 4;
constexpr size_t WROW_OFF = POS_OFF + (size_t)kT * 2 * 4;
// end ~373 MiB

__device__ __forceinline__ unsigned short f2bf(float x) {   // RNE f32->bf16
  unsigned int u = __float_as_uint(x);
  u += 0x7FFFu + ((u >> 16) & 1u);
  return (unsigned short)(u >> 16);
}
__device__ __forceinline__ unsigned pk2(float a, float b) {
  return (unsigned)f2bf(a) | ((unsigned)f2bf(b) << 16);
}
__device__ __forceinline__ float silu_f(float x) { return x / (1.f + __expf(-x)); }

__device__ __forceinline__ void async_copy16(void* lds, const void* g) {
  __builtin_amdgcn_global_load_lds(
      (const __attribute__((address_space(1))) void*)g,
      (__attribute__((address_space(3))) void*)lds, 16, 0, 0);
}

#define MFMA_BF16 __builtin_amdgcn_mfma_f32_16x16x32_bf16

// ---------------- kernel 1: fp32 -> bf16 hidden states ----------------
__global__ void cvt_hs_kernel(const float* __restrict__ in, unsigned short* __restrict__ out) {
  size_t i = ((size_t)blockIdx.x * 256 + threadIdx.x) * 8;
  float4 a = *(const float4*)(in + i);
  float4 b = *(const float4*)(in + i + 4);
  uint4 v;
  v.x = pk2(a.x, a.y); v.y = pk2(a.z, a.w);
  v.z = pk2(b.x, b.y); v.w = pk2(b.z, b.w);
  *(uint4*)(out + i) = v;
}

// ---------------- kernel 1b: transpose+convert (K,N) f32 -> (N,K) bf16 -------
__global__ __launch_bounds__(256)
void tcvt_kernel(const float* __restrict__ src, unsigned short* __restrict__ dst,
                 int K, int N) {
  __shared__ __attribute__((aligned(16))) unsigned short s[64][72];
  const size_t mat = (size_t)K * N;
  const float* S = src + (size_t)blockIdx.z * mat;
  unsigned short* D = dst + (size_t)blockIdx.z * mat;
  const int k0 = blockIdx.y * 64, n0 = blockIdx.x * 64;
  const int t  = threadIdx.x;
  const int n4 = (t & 15) * 4;
  const int k4 = (t >> 4) * 4;
  const float* p0 = S + (size_t)(k0 + k4) * N + n0 + n4;
  float4 r0 = *(const float4*)(p0);
  float4 r1 = *(const float4*)(p0 + N);
  float4 r2 = *(const float4*)(p0 + 2 * (size_t)N);
  float4 r3 = *(const float4*)(p0 + 3 * (size_t)N);
  uint2 v;
  v.x = pk2(r0.x, r1.x); v.y = pk2(r2.x, r3.x); *(uint2*)(&s[n4 + 0][k4]) = v;
  v.x = pk2(r0.y, r1.y); v.y = pk2(r2.y, r3.y); *(uint2*)(&s[n4 + 1][k4]) = v;
  v.x = pk2(r0.z, r1.z); v.y = pk2(r2.z, r3.z); *(uint2*)(&s[n4 + 2][k4]) = v;
  v.x = pk2(r0.w, r1.w); v.y = pk2(r2.w, r3.w); *(uint2*)(&s[n4 + 3][k4]) = v;
  __syncthreads();
  const int nn = t >> 3;
  const int kc = (t & 7) * 8;
#pragma unroll
  for (int i = 0; i < 2; ++i) {
    const int n = nn + i * 32;
    uint4 u = *(const uint4*)(&s[n][kc]);
    *(uint4*)(D + (size_t)(n0 + n) * K + k0 + kc) = u;
  }
}

// ---------------- kernel 2: routing ----------------
__global__ void route_kernel(const float* __restrict__ aff, const int* __restrict__ idx,
                             int* counts, int* ltok, float* lw, int* pos) {
  int t = blockIdx.x * 256 + threadIdx.x;
  if (t >= kT) return;
  int e0 = idx[t * 2 + 0];
  int e1 = idx[t * 2 + 1];
  float a0 = aff[t * kE + e0];
  float a1 = aff[t * kE + e1];
  if (e0 == e1) {
    float w = a0 / fmaxf(fabsf(a0), 1e-12f);
    int s = atomicAdd(&counts[e0], 1);
    ltok[e0 * kCap + s] = t;
    lw[e0 * kCap + s]   = w;
    pos[t * 2 + 0] = (e0 << 12) | s;
    pos[t * 2 + 1] = -1;
  } else {
    float d = fmaxf(fabsf(a0) + fabsf(a1), 1e-12f);
    int s0 = atomicAdd(&counts[e0], 1);
    ltok[e0 * kCap + s0] = t;
    lw[e0 * kCap + s0]   = a0 / d;
    int s1 = atomicAdd(&counts[e1], 1);
    ltok[e1 * kCap + s1] = t;
    lw[e1 * kCap + s1]   = a1 / d;
    pos[t * 2 + 0] = (e0 << 12) | s0;
    pos[t * 2 + 1] = (e1 << 12) | s1;
  }
}

// 256-aligned prefix offsets
__global__ void prefix_kernel(const int* __restrict__ counts, int* offs) {
  if (threadIdx.x == 0 && blockIdx.x == 0) {
    int acc = 0;
    for (int e = 0; e < kE; ++e) { offs[e] = acc; acc += (counts[e] + 255) & ~255; }
  }
}

// per-slot-row affinity weight (0 for align-pad rows)
__global__ void wrow_kernel(const int* __restrict__ counts, const int* __restrict__ offs,
                            const float* __restrict__ lw, float* __restrict__ wrow) {
  int idx = blockIdx.x * 256 + threadIdx.x;
  int e = idx >> 12, s = idx & 4095;
  int cnt = counts[e];
  int al  = (cnt + 255) & ~255;
  if (s < al) wrow[offs[e] + s] = (s < cnt) ? lw[e * kCap + s] : 0.f;
}

// ---------------- kernel 3: fused gate+up GEMM, ring-4 slice pipeline --------
// BM=256, BN=128, slice=32K. 8 waves (2m x 4n), per-wave 128m x 32n per matrix.
// LDS slice slot (32 KiB): A [256][32] @0, Wg [128][32] @16384B, Wu @24576B.
// grid (kI/128, kCap/256, E), 512 threads.
__global__ __launch_bounds__(512, 2)
void gemm_gu_kernel(const unsigned short* __restrict__ hsb,
                    const unsigned short* __restrict__ wgT,   // (E, I, H) bf16
                    const unsigned short* __restrict__ wuT,
                    const int* __restrict__ counts, const int* __restrict__ offs,
                    const int* __restrict__ ltok, const float* __restrict__ wrow,
                    unsigned short* __restrict__ hbuf) {
  constexpr int S = kH / 32;   // 64 slices
  __shared__ __attribute__((aligned(16))) unsigned short lds[4 * 16384];

  const int e   = blockIdx.z;
  const int cnt = counts[e];
  const int m0  = blockIdx.y * 256;
  if (m0 >= cnt) return;
  const int n0   = blockIdx.x * 128;
  const int tid  = threadIdx.x;
  const int lane = tid & 63;
  const int wv   = tid >> 6;
  const int wm   = wv >> 2;       // 2 m-halves of 128
  const int wn   = wv & 3;        // 4 n-panels of 32
  const int baseRow = offs[e] + m0;

  // staging: chunk (row = tid>>2, physical slot = tid&3) holds logical slot
  // (tid&3)^((row>>1)&3) = (tid&3)^((tid>>3)&3)  [involution]
  const int skof = ((tid & 3) ^ ((tid >> 3) & 3)) * 8;   // source k offset (bf16)
  int sl0 = m0 + (tid >> 2);        sl0 = sl0 < cnt ? sl0 : cnt - 1;
  int sl1 = m0 + 128 + (tid >> 2);  sl1 = sl1 < cnt ? sl1 : cnt - 1;
  const unsigned short* aP0 = hsb + (size_t)ltok[e * kCap + sl0] * kH + skof;
  const unsigned short* aP1 = hsb + (size_t)ltok[e * kCap + sl1] * kH + skof;
  const unsigned short* wgP = wgT + (size_t)e * kI * kH
                                  + (size_t)(n0 + (tid >> 2)) * kH + skof;
  const unsigned short* wuP = wuT + (size_t)e * kI * kH
                                  + (size_t)(n0 + (tid >> 2)) * kH + skof;
  char* ldsb = (char*)lds;
  const int aO0 = tid * 16;
  const int aO1 = aO0 + 8192;
  const int wO  = tid * 16;

#define GU_STG_A(s) { const int sb_ = ((s) & 3) * 32768; const int ko_ = (s) * 32;  \
    async_copy16(ldsb + sb_ + aO0, aP0 + ko_);                                      \
    async_copy16(ldsb + sb_ + aO1, aP1 + ko_); }
#define GU_STG_W(s) { const int sb_ = ((s) & 3) * 32768; const int ko_ = (s) * 32;  \
    async_copy16(ldsb + sb_ + 16384 + wO, wgP + ko_);                               \
    async_copy16(ldsb + sb_ + 24576 + wO, wuP + ko_); }

  f32x4 accG[8][2] = {};
  f32x4 accU[8][2] = {};
  const int ar = lane & 15;
  // read-side k-slot with XOR swizzle folded in: rows are base+ar with base
  // multiple of 16, so (row>>1)&3 = (lane>>1)&3 -> per-lane constant.
  const int fo = (((lane >> 4) ^ ((lane >> 1) & 3)) << 4);

  // ONE barrier per slice: stage issue early, 12 reads, 32 MFMA, vmcnt, barrier.
#define GU_SLICE(s, STG, VM)                                                         \
  {                                                                                  \
    const char* sb = ldsb + ((s) & 3) * 32768;                                       \
    if (STG) { GU_STG_A((s) + 3); GU_STG_W((s) + 3); }                               \
    bf16x8 fA[8], fWg[2], fWu[2];                                                    \
    _Pragma("unroll") for (int mf = 0; mf < 8; ++mf)                                 \
      fA[mf] = *(const bf16x8*)(sb + (wm * 128 + mf * 16 + ar) * 64 + fo);           \
    _Pragma("unroll") for (int nf = 0; nf < 2; ++nf) {                               \
      fWg[nf] = *(const bf16x8*)(sb + 16384 + (wn * 32 + nf * 16 + ar) * 64 + fo);   \
      fWu[nf] = *(const bf16x8*)(sb + 24576 + (wn * 32 + nf * 16 + ar) * 64 + fo);   \
    }                                                                                \
    __builtin_amdgcn_s_setprio(1);                                                   \
    _Pragma("unroll") for (int mf = 0; mf < 8; ++mf)                                 \
      _Pragma("unroll") for (int nf = 0; nf < 2; ++nf) {                             \
        accG[mf][nf] = MFMA_BF16(fWg[nf], fA[mf], accG[mf][nf], 0, 0, 0);            \
        accU[mf][nf] = MFMA_BF16(fWu[nf], fA[mf], accU[mf][nf], 0, 0, 0);            \
      }                                                                              \
    __builtin_amdgcn_s_setprio(0);                                                   \
    if ((VM) >= 0) {                                                                 \
      asm volatile("s_waitcnt vmcnt(%0)" :: "i"((VM) < 0 ? 0 : (VM)) : "memory");    \
      __builtin_amdgcn_s_barrier();                                                  \
    }                                                                                \
  }

  // prologue: slices 0,1,2 in flight; wait slice 0
  GU_STG_A(0); GU_STG_W(0);
  GU_STG_A(1); GU_STG_W(1);
  GU_STG_A(2); GU_STG_W(2);
  asm volatile("s_waitcnt vmcnt(8)" ::: "memory");
  __builtin_amdgcn_s_barrier();

  for (int s = 0; s < S - 3; ++s) GU_SLICE(s, true, 8);
  GU_SLICE(S - 3, false, 4);
  GU_SLICE(S - 2, false, 0);
  GU_SLICE(S - 1, false, -1);
#undef GU_SLICE
#undef GU_STG_A
#undef GU_STG_W

  // epilogue: h = silu(g)*u*wrow -> bf16 hbuf
  const int lr4 = (lane >> 4) * 4;
#pragma unroll
  for (int mf = 0; mf < 8; ++mf) {
    const int grow = baseRow + wm * 128 + mf * 16 + ar;
    const float wf = wrow[grow];
#pragma unroll
    for (int nf = 0; nf < 2; ++nf) {
      const int n = n0 + wn * 32 + nf * 16 + lr4;
      f32x4 g = accG[mf][nf], u = accU[mf][nf];
      float h0 = silu_f(g[0]) * u[0] * wf;
      float h1 = silu_f(g[1]) * u[1] * wf;
      float h2 = silu_f(g[2]) * u[2] * wf;
      float h3 = silu_f(g[3]) * u[3] * wf;
      uint2 v;
      v.x = pk2(h0, h1);
      v.y = pk2(h2, h3);
      *(uint2*)(hbuf + ((size_t)grow * kI + n)) = v;
    }
  }
}

// ---------------- kernel 4: down GEMM, ring-4 slice pipeline ----------------
// BM=256, BN=256, slice=32K. 8 waves (2m x 4n), per-wave 128m x 64n.
// LDS slot (32 KiB): A [256][32] @0, W [256][32] @16384B.
// grid (kH/256, kCap/256, E), 512 threads.
__global__ __launch_bounds__(512, 2)
void gemm_dn_kernel(const unsigned short* __restrict__ hbuf,
                    const unsigned short* __restrict__ wdT,   // (E, H, I) bf16
                    const int* __restrict__ counts, const int* __restrict__ offs,
                    float* __restrict__ obuf) {
  constexpr int S = kI / 32;   // 128 slices
  __shared__ __attribute__((aligned(16))) unsigned short lds[4 * 16384];

  const int e   = blockIdx.z;
  const int cnt = counts[e];
  const int m0  = blockIdx.y * 256;
  if (m0 >= cnt) return;
  const int n0   = blockIdx.x * 256;
  const int tid  = threadIdx.x;
  const int lane = tid & 63;
  const int wv   = tid >> 6;
  const int wm   = wv >> 2;
  const int wn   = wv & 3;
  const int baseRow = offs[e] + m0;

  const int skof = ((tid & 3) ^ ((tid >> 3) & 3)) * 8;   // pre-swizzled source k
  const unsigned short* aP0 = hbuf + (size_t)(baseRow + (tid >> 2)) * kI + skof;
  const unsigned short* aP1 = hbuf + (size_t)(baseRow + 128 + (tid >> 2)) * kI + skof;
  const unsigned short* wP0 = wdT + (size_t)e * kH * kI
                                  + (size_t)(n0 + (tid >> 2)) * kI + skof;
  const unsigned short* wP1 = wdT + (size_t)e * kH * kI
                                  + (size_t)(n0 + 128 + (tid >> 2)) * kI + skof;
  char* ldsb = (char*)lds;
  const int cO0 = tid * 16;
  const int cO1 = cO0 + 8192;

#define DN_STG_A(s) { const int sb_ = ((s) & 3) * 32768; const int ko_ = (s) * 32;  \
    async_copy16(ldsb + sb_ + cO0, aP0 + ko_);                                      \
    async_copy16(ldsb + sb_ + cO1, aP1 + ko_); }
#define DN_STG_W(s) { const int sb_ = ((s) & 3) * 32768; const int ko_ = (s) * 32;  \
    async_copy16(ldsb + sb_ + 16384 + cO0, wP0 + ko_);                              \
    async_copy16(ldsb + sb_ + 16384 + cO1, wP1 + ko_); }

  f32x4 acc[8][4] = {};
  const int ar = lane & 15;
  const int fo = (((lane >> 4) ^ ((lane >> 1) & 3)) << 4);

#define DN_SLICE(s, STG, VM)                                                         \
  {                                                                                  \
    const char* sb = ldsb + ((s) & 3) * 32768;                                       \
    if (STG) { DN_STG_A((s) + 3); DN_STG_W((s) + 3); }                               \
    bf16x8 fA[8], fW[4];                                                             \
    _Pragma("unroll") for (int mf = 0; mf < 8; ++mf)                                 \
      fA[mf] = *(const bf16x8*)(sb + (wm * 128 + mf * 16 + ar) * 64 + fo);           \
    _Pragma("unroll") for (int nf = 0; nf < 4; ++nf)                                 \
      fW[nf] = *(const bf16x8*)(sb + 16384 + (wn * 64 + nf * 16 + ar) * 64 + fo);    \
    __builtin_amdgcn_s_setprio(1);                                                   \
    _Pragma("unroll") for (int mf = 0; mf < 8; ++mf)                                 \
      _Pragma("unroll") for (int nf = 0; nf < 4; ++nf)                               \
        acc[mf][nf] = MFMA_BF16(fW[nf], fA[mf], acc[mf][nf], 0, 0, 0);               \
    __builtin_amdgcn_s_setprio(0);                                                   \
    if ((VM) >= 0) {                                                                 \
      asm volatile("s_waitcnt vmcnt(%0)" :: "i"((VM) < 0 ? 0 : (VM)) : "memory");    \
      __builtin_amdgcn_s_barrier();                                                  \
    }                                                                                \
  }

  DN_STG_A(0); DN_STG_W(0);
  DN_STG_A(1); DN_STG_W(1);
  DN_STG_A(2); DN_STG_W(2);
  asm volatile("s_waitcnt vmcnt(8)" ::: "memory");
  __builtin_amdgcn_s_barrier();

  for (int s = 0; s < S - 3; ++s) DN_SLICE(s, true, 8);
  DN_SLICE(S - 3, false, 4);
  DN_SLICE(S - 2, false, 0);
  DN_SLICE(S - 1, false, -1);
#undef DN_SLICE
#undef DN_STG_A
#undef DN_STG_W

  const int lr4 = (lane >> 4) * 4;
#pragma unroll
  for (int mf = 0; mf < 8; ++mf) {
    const int grow = baseRow + wm * 128 + mf * 16 + ar;
#pragma unroll
    for (int nf = 0; nf < 4; ++nf) {
      const int n = n0 + wn * 64 + nf * 16 + lr4;
      *(f32x4*)(obuf + (size_t)grow * kH + n) = acc[mf][nf];
    }
  }
}

// ---------------- kernel 5: combine obuf slots -> out ----------------
__global__ void combine_kernel(const float* __restrict__ obuf,
                               const int* __restrict__ pos,
                               const int* __restrict__ offs,
                               float* __restrict__ out) {
  const int t   = blockIdx.y;
  const int col = blockIdx.x * 1024 + threadIdx.x * 4;
  const int c0  = pos[t * 2 + 0];
  const int c1  = pos[t * 2 + 1];
  const int row0 = offs[c0 >> 12] + (c0 & 4095);
  float4 v = *(const float4*)(obuf + (size_t)row0 * kH + col);
  if (c1 >= 0) {
    const int row1 = offs[c1 >> 12] + (c1 & 4095);
    float4 w = *(const float4*)(obuf + (size_t)row1 * kH + col);
    v.x += w.x; v.y += w.y; v.z += w.z; v.w += w.w;
  }
  *(float4*)(out + (size_t)t * kH + col) = v;
}

// ---------------- launcher ----------------
extern "C" void kernel_launch(void* const* d_in, const int* in_sizes, int n_in,
                              void* d_out, int out_size, void* d_ws, size_t ws_size,
                              hipStream_t stream) {
  const float* hs   = (const float*)d_in[0];
  const float* aff  = (const float*)d_in[1];
  const int*   eidx = (const int*)d_in[2];
  const float* wg   = (const float*)d_in[3];
  const float* wu   = (const float*)d_in[4];
  const float* wd   = (const float*)d_in[5];
  float* out = (float*)d_out;

  char* ws = (char*)d_ws;
  unsigned short* hsb  = (unsigned short*)(ws + HSB_OFF);
  unsigned short* hbuf = (unsigned short*)(ws + HBUF_OFF);
  unsigned short* wgT  = (unsigned short*)(ws + RA_OFF);   // later: wdT
  unsigned short* wdT  = (unsigned short*)(ws + RA_OFF);
  unsigned short* wuT  = (unsigned short*)(ws + RB_OFF);   // later: obuf
  float*          obuf = (float*)(ws + RB_OFF);
  int*            cnts = (int*)(ws + CNT_OFF);
  int*            offs = (int*)(ws + OFF_OFF);
  int*            ltok = (int*)(ws + LTOK_OFF);
  float*          lwgt = (float*)(ws + LW_OFF);
  int*            pos  = (int*)(ws + POS_OFF);
  float*          wrow = (float*)(ws + WROW_OFF);

  hipMemsetAsync(cnts, 0, kE * sizeof(int), stream);

  cvt_hs_kernel<<<(kT * kH) / (256 * 8), 256, 0, stream>>>(hs, hsb);
  route_kernel<<<kT / 256, 256, 0, stream>>>(aff, eidx, cnts, ltok, lwgt, pos);
  prefix_kernel<<<1, 64, 0, stream>>>(cnts, offs);
  wrow_kernel<<<(kE * kCap) / 256, 256, 0, stream>>>(cnts, offs, lwgt, wrow);

  tcvt_kernel<<<dim3(kI / 64, kH / 64, kE), 256, 0, stream>>>(wg, wgT, kH, kI);
  tcvt_kernel<<<dim3(kI / 64, kH / 64, kE), 256, 0, stream>>>(wu, wuT, kH, kI);

  gemm_gu_kernel<<<dim3(kI / 128, kCap / 256, kE), 512, 0, stream>>>(
      hsb, wgT, wuT, cnts, offs, ltok, wrow, hbuf);

  tcvt_kernel<<<dim3(kH / 64, kI / 64, kE), 256, 0, stream>>>(wd, wdT, kI, kH);

  gemm_dn_kernel<<<dim3(kH / 256, kCap / 256, kE), 512, 0, stream>>>(
      hbuf, wdT, cnts, offs, obuf);

  combine_kernel<<<dim3(kH / 1024, kT), 256, 0, stream>>>(obuf, pos, offs, out);
}

// Round 11
// 774.913 us; speedup vs baseline: 1.0013x; 1.0013x over previous
//
#include <hip/hip_runtime.h>
#include <hip/hip_bf16.h>

// ExpertMLPsV2: T=4096, H=2048, I=4096, E=8, TOPK=2.
// cvt/route -> tcvt weights bf16 (N,K) -> fused gate+up GEMM -> tcvt wd ->
// down GEMM -> combine.
// GEMMs: ring-4 slice pipeline (BK=32) with REGISTER FRAG DOUBLE-BUFFER:
// during slice s the wave MFMAs on A-frags loaded last slice while ds_reading
// slice s+1's A-frags (decouples lgkm latency from the MFMA cluster).
// Body: stage(s+3) -> W-frags(s) -> A-frags(s+1) -> 32 MFMA -> vmcnt(4)
// lgkmcnt(0) + barrier. Stage writes slot (s-1)&3, whose reads drained at the
// previous boundary's lgkmcnt(0) - clobber-safe by construction.
// LDS: linear dest for DMA; 16B k-slot XOR swizzle (s^((row>>1)&3)) via
// pre-swizzled source; read-side XOR folds into per-lane constant fo. 0 conflicts.

constexpr int kT   = 4096;
constexpr int kH   = 2048;
constexpr int kI   = 4096;
constexpr int kE   = 8;
constexpr int kCap = 4096;
constexpr int kRowsCap = 10240;

typedef __attribute__((ext_vector_type(8))) short bf16x8;
typedef __attribute__((ext_vector_type(4))) float f32x4;

// ---------------- workspace layout ----------------
constexpr size_t HSB_OFF  = 0;                                      // hs bf16 16 MiB
constexpr size_t HBUF_OFF = 16777216;                               // h bf16 rowsCap x kI (80 MiB)
constexpr size_t RA_OFF   = HBUF_OFF + (size_t)kRowsCap * kI * 2;   // wgT -> wdT (128 MiB)
constexpr size_t RB_OFF   = RA_OFF + (size_t)kE * kH * kI * 2;      // wuT -> obuf (128 MiB)
constexpr size_t CNT_OFF  = RB_OFF + (size_t)kE * kH * kI * 2;
constexpr size_t OFF_OFF  = CNT_OFF + 256;
constexpr size_t LTOK_OFF = OFF_OFF + 256;
constexpr size_t LW_OFF   = LTOK_OFF + (size_t)kE * kCap * 4;
constexpr size_t POS_OFF  = LW_OFF + (size_t)kE * kCap * 4;
constexpr size_t WROW_OFF = POS_OFF + (size_t)kT * 2 * 4;
// end ~373 MiB

__device__ __forceinline__ unsigned short f2bf(float x) {   // RNE f32->bf16
  unsigned int u = __float_as_uint(x);
  u += 0x7FFFu + ((u >> 16) & 1u);
  return (unsigned short)(u >> 16);
}
__device__ __forceinline__ unsigned pk2(float a, float b) {
  return (unsigned)f2bf(a) | ((unsigned)f2bf(b) << 16);
}
__device__ __forceinline__ float silu_f(float x) { return x / (1.f + __expf(-x)); }

__device__ __forceinline__ void async_copy16(void* lds, const void* g) {
  __builtin_amdgcn_global_load_lds(
      (const __attribute__((address_space(1))) void*)g,
      (__attribute__((address_space(3))) void*)lds, 16, 0, 0);
}

#define MFMA_BF16 __builtin_amdgcn_mfma_f32_16x16x32_bf16

// ---------------- kernel 1: fp32 -> bf16 hidden states ----------------
__global__ void cvt_hs_kernel(const float* __restrict__ in, unsigned short* __restrict__ out) {
  size_t i = ((size_t)blockIdx.x * 256 + threadIdx.x) * 8;
  float4 a = *(const float4*)(in + i);
  float4 b = *(const float4*)(in + i + 4);
  uint4 v;
  v.x = pk2(a.x, a.y); v.y = pk2(a.z, a.w);
  v.z = pk2(b.x, b.y); v.w = pk2(b.z, b.w);
  *(uint4*)(out + i) = v;
}

// ---------------- kernel 1b: transpose+convert (K,N) f32 -> (N,K) bf16 -------
__global__ __launch_bounds__(256)
void tcvt_kernel(const float* __restrict__ src, unsigned short* __restrict__ dst,
                 int K, int N) {
  __shared__ __attribute__((aligned(16))) unsigned short s[64][72];
  const size_t mat = (size_t)K * N;
  const float* S = src + (size_t)blockIdx.z * mat;
  unsigned short* D = dst + (size_t)blockIdx.z * mat;
  const int k0 = blockIdx.y * 64, n0 = blockIdx.x * 64;
  const int t  = threadIdx.x;
  const int n4 = (t & 15) * 4;
  const int k4 = (t >> 4) * 4;
  const float* p0 = S + (size_t)(k0 + k4) * N + n0 + n4;
  float4 r0 = *(const float4*)(p0);
  float4 r1 = *(const float4*)(p0 + N);
  float4 r2 = *(const float4*)(p0 + 2 * (size_t)N);
  float4 r3 = *(const float4*)(p0 + 3 * (size_t)N);
  uint2 v;
  v.x = pk2(r0.x, r1.x); v.y = pk2(r2.x, r3.x); *(uint2*)(&s[n4 + 0][k4]) = v;
  v.x = pk2(r0.y, r1.y); v.y = pk2(r2.y, r3.y); *(uint2*)(&s[n4 + 1][k4]) = v;
  v.x = pk2(r0.z, r1.z); v.y = pk2(r2.z, r3.z); *(uint2*)(&s[n4 + 2][k4]) = v;
  v.x = pk2(r0.w, r1.w); v.y = pk2(r2.w, r3.w); *(uint2*)(&s[n4 + 3][k4]) = v;
  __syncthreads();
  const int nn = t >> 3;
  const int kc = (t & 7) * 8;
#pragma unroll
  for (int i = 0; i < 2; ++i) {
    const int n = nn + i * 32;
    uint4 u = *(const uint4*)(&s[n][kc]);
    *(uint4*)(D + (size_t)(n0 + n) * K + k0 + kc) = u;
  }
}

// ---------------- kernel 2: routing ----------------
__global__ void route_kernel(const float* __restrict__ aff, const int* __restrict__ idx,
                             int* counts, int* ltok, float* lw, int* pos) {
  int t = blockIdx.x * 256 + threadIdx.x;
  if (t >= kT) return;
  int e0 = idx[t * 2 + 0];
  int e1 = idx[t * 2 + 1];
  float a0 = aff[t * kE + e0];
  float a1 = aff[t * kE + e1];
  if (e0 == e1) {
    float w = a0 / fmaxf(fabsf(a0), 1e-12f);
    int s = atomicAdd(&counts[e0], 1);
    ltok[e0 * kCap + s] = t;
    lw[e0 * kCap + s]   = w;
    pos[t * 2 + 0] = (e0 << 12) | s;
    pos[t * 2 + 1] = -1;
  } else {
    float d = fmaxf(fabsf(a0) + fabsf(a1), 1e-12f);
    int s0 = atomicAdd(&counts[e0], 1);
    ltok[e0 * kCap + s0] = t;
    lw[e0 * kCap + s0]   = a0 / d;
    int s1 = atomicAdd(&counts[e1], 1);
    ltok[e1 * kCap + s1] = t;
    lw[e1 * kCap + s1]   = a1 / d;
    pos[t * 2 + 0] = (e0 << 12) | s0;
    pos[t * 2 + 1] = (e1 << 12) | s1;
  }
}

// 256-aligned prefix offsets
__global__ void prefix_kernel(const int* __restrict__ counts, int* offs) {
  if (threadIdx.x == 0 && blockIdx.x == 0) {
    int acc = 0;
    for (int e = 0; e < kE; ++e) { offs[e] = acc; acc += (counts[e] + 255) & ~255; }
  }
}

// per-slot-row affinity weight (0 for align-pad rows)
__global__ void wrow_kernel(const int* __restrict__ counts, const int* __restrict__ offs,
                            const float* __restrict__ lw, float* __restrict__ wrow) {
  int idx = blockIdx.x * 256 + threadIdx.x;
  int e = idx >> 12, s = idx & 4095;
  int cnt = counts[e];
  int al  = (cnt + 255) & ~255;
  if (s < al) wrow[offs[e] + s] = (s < cnt) ? lw[e * kCap + s] : 0.f;
}

// ---------------- kernel 3: fused gate+up GEMM, ring-4 + frag dbuf ----------
// BM=256, BN=128, slice=32K. 8 waves (2m x 4n), per-wave 128m x 32n per matrix.
// LDS slot (32 KiB): A [256][32] @0, Wg [128][32] @16384B, Wu @24576B.
// grid (kI/128, kCap/256, E), 512 threads.
__global__ __launch_bounds__(512, 2)
void gemm_gu_kernel(const unsigned short* __restrict__ hsb,
                    const unsigned short* __restrict__ wgT,   // (E, I, H) bf16
                    const unsigned short* __restrict__ wuT,
                    const int* __restrict__ counts, const int* __restrict__ offs,
                    const int* __restrict__ ltok, const float* __restrict__ wrow,
                    unsigned short* __restrict__ hbuf) {
  constexpr int S = kH / 32;   // 64 slices
  __shared__ __attribute__((aligned(16))) unsigned short lds[4 * 16384];

  const int e   = blockIdx.z;
  const int cnt = counts[e];
  const int m0  = blockIdx.y * 256;
  if (m0 >= cnt) return;
  const int n0   = blockIdx.x * 128;
  const int tid  = threadIdx.x;
  const int lane = tid & 63;
  const int wv   = tid >> 6;
  const int wm   = wv >> 2;       // 2 m-halves of 128
  const int wn   = wv & 3;        // 4 n-panels of 32
  const int baseRow = offs[e] + m0;

  const int skof = ((tid & 3) ^ ((tid >> 3) & 3)) * 8;   // pre-swizzled source k
  int sl0 = m0 + (tid >> 2);        sl0 = sl0 < cnt ? sl0 : cnt - 1;
  int sl1 = m0 + 128 + (tid >> 2);  sl1 = sl1 < cnt ? sl1 : cnt - 1;
  const unsigned short* aP0 = hsb + (size_t)ltok[e * kCap + sl0] * kH + skof;
  const unsigned short* aP1 = hsb + (size_t)ltok[e * kCap + sl1] * kH + skof;
  const unsigned short* wgP = wgT + (size_t)e * kI * kH
                                  + (size_t)(n0 + (tid >> 2)) * kH + skof;
  const unsigned short* wuP = wuT + (size_t)e * kI * kH
                                  + (size_t)(n0 + (tid >> 2)) * kH + skof;
  char* ldsb = (char*)lds;
  const int aO0 = tid * 16;
  const int aO1 = aO0 + 8192;
  const int wO  = tid * 16;

#define GU_STG_A(s) { const int sb_ = ((s) & 3) * 32768; const int ko_ = (s) * 32;  \
    async_copy16(ldsb + sb_ + aO0, aP0 + ko_);                                      \
    async_copy16(ldsb + sb_ + aO1, aP1 + ko_); }
#define GU_STG_W(s) { const int sb_ = ((s) & 3) * 32768; const int ko_ = (s) * 32;  \
    async_copy16(ldsb + sb_ + 16384 + wO, wgP + ko_);                               \
    async_copy16(ldsb + sb_ + 24576 + wO, wuP + ko_); }

  f32x4 accG[8][2] = {};
  f32x4 accU[8][2] = {};
  const int ar = lane & 15;
  const int fo = (((lane >> 4) ^ ((lane >> 1) & 3)) << 4);

  // Body of slice s: stage(s+3) [writes slot (s-1)&3, drained reads], W-frags(s),
  // A-frags(s+1) into NXT, MFMA on CUR, boundary vmcnt(4)+lgkmcnt(0)+barrier.
#define GU_BODY(s, CUR, NXT, STG, RD, VM)                                            \
  {                                                                                  \
    const char* sbc = ldsb + ((s) & 3) * 32768;                                      \
    const char* sbn = ldsb + (((s) + 1) & 3) * 32768;                                \
    if (STG) { GU_STG_A((s) + 3); GU_STG_W((s) + 3); }                               \
    bf16x8 wg_[2], wu_[2];                                                           \
    _Pragma("unroll") for (int nf = 0; nf < 2; ++nf) {                               \
      wg_[nf] = *(const bf16x8*)(sbc + 16384 + (wn * 32 + nf * 16 + ar) * 64 + fo);  \
      wu_[nf] = *(const bf16x8*)(sbc + 24576 + (wn * 32 + nf * 16 + ar) * 64 + fo);  \
    }                                                                                \
    if (RD) {                                                                        \
      _Pragma("unroll") for (int mf = 0; mf < 8; ++mf)                               \
        NXT[mf] = *(const bf16x8*)(sbn + (wm * 128 + mf * 16 + ar) * 64 + fo);       \
    }                                                                                \
    __builtin_amdgcn_s_setprio(1);                                                   \
    _Pragma("unroll") for (int mf = 0; mf < 8; ++mf)                                 \
      _Pragma("unroll") for (int nf = 0; nf < 2; ++nf) {                             \
        accG[mf][nf] = MFMA_BF16(wg_[nf], CUR[mf], accG[mf][nf], 0, 0, 0);           \
        accU[mf][nf] = MFMA_BF16(wu_[nf], CUR[mf], accU[mf][nf], 0, 0, 0);           \
      }                                                                              \
    __builtin_amdgcn_s_setprio(0);                                                   \
    if ((VM) >= 0) {                                                                 \
      asm volatile("s_waitcnt vmcnt(%0) lgkmcnt(0)" :: "i"((VM) < 0 ? 0 : (VM)) : "memory"); \
      __builtin_amdgcn_s_barrier();                                                  \
    }                                                                                \
  }

  // prologue: slices 0,1,2 in flight; drain 0,1; preload A-frags(0)
  GU_STG_A(0); GU_STG_W(0);
  GU_STG_A(1); GU_STG_W(1);
  GU_STG_A(2); GU_STG_W(2);
  asm volatile("s_waitcnt vmcnt(4)" ::: "memory");
  __builtin_amdgcn_s_barrier();

  bf16x8 aA[8], aB[8];
#pragma unroll
  for (int mf = 0; mf < 8; ++mf)
    aA[mf] = *(const bf16x8*)(ldsb + (wm * 128 + mf * 16 + ar) * 64 + fo);

  for (int s = 0; s < S - 4; s += 2) {
    GU_BODY(s,     aA, aB, 1, 1, 4);
    GU_BODY(s + 1, aB, aA, 1, 1, 4);
  }
  GU_BODY(S - 4, aA, aB, 1, 1, 4);   // stages slice S-1
  GU_BODY(S - 3, aB, aA, 0, 1, 0);
  GU_BODY(S - 2, aA, aB, 0, 1, -1);
  GU_BODY(S - 1, aB, aA, 0, 0, -1);
#undef GU_BODY
#undef GU_STG_A
#undef GU_STG_W

  // epilogue: h = silu(g)*u*wrow -> bf16 hbuf
  const int lr4 = (lane >> 4) * 4;
#pragma unroll
  for (int mf = 0; mf < 8; ++mf) {
    const int grow = baseRow + wm * 128 + mf * 16 + ar;
    const float wf = wrow[grow];
#pragma unroll
    for (int nf = 0; nf < 2; ++nf) {
      const int n = n0 + wn * 32 + nf * 16 + lr4;
      f32x4 g = accG[mf][nf], u = accU[mf][nf];
      float h0 = silu_f(g[0]) * u[0] * wf;
      float h1 = silu_f(g[1]) * u[1] * wf;
      float h2 = silu_f(g[2]) * u[2] * wf;
      float h3 = silu_f(g[3]) * u[3] * wf;
      uint2 v;
      v.x = pk2(h0, h1);
      v.y = pk2(h2, h3);
      *(uint2*)(hbuf + ((size_t)grow * kI + n)) = v;
    }
  }
}

// ---------------- kernel 4: down GEMM, ring-4 + frag dbuf ----------------
// BM=256, BN=256, slice=32K. 8 waves (2m x 4n), per-wave 128m x 64n.
// LDS slot (32 KiB): A [256][32] @0, W [256][32] @16384B.
// grid (kH/256, kCap/256, E), 512 threads.
__global__ __launch_bounds__(512, 2)
void gemm_dn_kernel(const unsigned short* __restrict__ hbuf,
                    const unsigned short* __restrict__ wdT,   // (E, H, I) bf16
                    const int* __restrict__ counts, const int* __restrict__ offs,
                    float* __restrict__ obuf) {
  constexpr int S = kI / 32;   // 128 slices
  __shared__ __attribute__((aligned(16))) unsigned short lds[4 * 16384];

  const int e   = blockIdx.z;
  const int cnt = counts[e];
  const int m0  = blockIdx.y * 256;
  if (m0 >= cnt) return;
  const int n0   = blockIdx.x * 256;
  const int tid  = threadIdx.x;
  const int lane = tid & 63;
  const int wv   = tid >> 6;
  const int wm   = wv >> 2;
  const int wn   = wv & 3;
  const int baseRow = offs[e] + m0;

  const int skof = ((tid & 3) ^ ((tid >> 3) & 3)) * 8;
  const unsigned short* aP0 = hbuf + (size_t)(baseRow + (tid >> 2)) * kI + skof;
  const unsigned short* aP1 = hbuf + (size_t)(baseRow + 128 + (tid >> 2)) * kI + skof;
  const unsigned short* wP0 = wdT + (size_t)e * kH * kI
                                  + (size_t)(n0 + (tid >> 2)) * kI + skof;
  const unsigned short* wP1 = wdT + (size_t)e * kH * kI
                                  + (size_t)(n0 + 128 + (tid >> 2)) * kI + skof;
  char* ldsb = (char*)lds;
  const int cO0 = tid * 16;
  const int cO1 = cO0 + 8192;

#define DN_STG_A(s) { const int sb_ = ((s) & 3) * 32768; const int ko_ = (s) * 32;  \
    async_copy16(ldsb + sb_ + cO0, aP0 + ko_);                                      \
    async_copy16(ldsb + sb_ + cO1, aP1 + ko_); }
#define DN_STG_W(s) { const int sb_ = ((s) & 3) * 32768; const int ko_ = (s) * 32;  \
    async_copy16(ldsb + sb_ + 16384 + cO0, wP0 + ko_);                              \
    async_copy16(ldsb + sb_ + 16384 + cO1, wP1 + ko_); }

  f32x4 acc[8][4] = {};
  const int ar = lane & 15;
  const int fo = (((lane >> 4) ^ ((lane >> 1) & 3)) << 4);

#define DN_BODY(s, CUR, NXT, STG, RD, VM)                                            \
  {                                                                                  \
    const char* sbc = ldsb + ((s) & 3) * 32768;                                      \
    const char* sbn = ldsb + (((s) + 1) & 3) * 32768;                                \
    if (STG) { DN_STG_A((s) + 3); DN_STG_W((s) + 3); }                               \
    bf16x8 fW[4];                                                                    \
    _Pragma("unroll") for (int nf = 0; nf < 4; ++nf)                                 \
      fW[nf] = *(const bf16x8*)(sbc + 16384 + (wn * 64 + nf * 16 + ar) * 64 + fo);   \
    if (RD) {                                                                        \
      _Pragma("unroll") for (int mf = 0; mf < 8; ++mf)                               \
        NXT[mf] = *(const bf16x8*)(sbn + (wm * 128 + mf * 16 + ar) * 64 + fo);       \
    }                                                                                \
    __builtin_amdgcn_s_setprio(1);                                                   \
    _Pragma("unroll") for (int mf = 0; mf < 8; ++mf)                                 \
      _Pragma("unroll") for (int nf = 0; nf < 4; ++nf)                               \
        acc[mf][nf] = MFMA_BF16(fW[nf], CUR[mf], acc[mf][nf], 0, 0, 0);              \
    __builtin_amdgcn_s_setprio(0);                                                   \
    if ((VM) >= 0) {                                                                 \
      asm volatile("s_waitcnt vmcnt(%0) lgkmcnt(0)" :: "i"((VM) < 0 ? 0 : (VM)) : "memory"); \
      __builtin_amdgcn_s_barrier();                                                  \
    }                                                                                \
  }

  DN_STG_A(0); DN_STG_W(0);
  DN_STG_A(1); DN_STG_W(1);
  DN_STG_A(2); DN_STG_W(2);
  asm volatile("s_waitcnt vmcnt(4)" ::: "memory");
  __builtin_amdgcn_s_barrier();

  bf16x8 aA[8], aB[8];
#pragma unroll
  for (int mf = 0; mf < 8; ++mf)
    aA[mf] = *(const bf16x8*)(ldsb + (wm * 128 + mf * 16 + ar) * 64 + fo);

  for (int s = 0; s < S - 4; s += 2) {
    DN_BODY(s,     aA, aB, 1, 1, 4);
    DN_BODY(s + 1, aB, aA, 1, 1, 4);
  }
  DN_BODY(S - 4, aA, aB, 1, 1, 4);   // stages slice S-1
  DN_BODY(S - 3, aB, aA, 0, 1, 0);
  DN_BODY(S - 2, aA, aB, 0, 1, -1);
  DN_BODY(S - 1, aB, aA, 0, 0, -1);
#undef DN_BODY
#undef DN_STG_A
#undef DN_STG_W

  const int lr4 = (lane >> 4) * 4;
#pragma unroll
  for (int mf = 0; mf < 8; ++mf) {
    const int grow = baseRow + wm * 128 + mf * 16 + ar;
#pragma unroll
    for (int nf = 0; nf < 4; ++nf) {
      const int n = n0 + wn * 64 + nf * 16 + lr4;
      *(f32x4*)(obuf + (size_t)grow * kH + n) = acc[mf][nf];
    }
  }
}

// ---------------- kernel 5: combine obuf slots -> out ----------------
__global__ void combine_kernel(const float* __restrict__ obuf,
                               const int* __restrict__ pos,
                               const int* __restrict__ offs,
                               float* __restrict__ out) {
  const int t   = blockIdx.y;
  const int col = blockIdx.x * 1024 + threadIdx.x * 4;
  const int c0  = pos[t * 2 + 0];
  const int c1  = pos[t * 2 + 1];
  const int row0 = offs[c0 >> 12] + (c0 & 4095);
  float4 v = *(const float4*)(obuf + (size_t)row0 * kH + col);
  if (c1 >= 0) {
    const int row1 = offs[c1 >> 12] + (c1 & 4095);
    float4 w = *(const float4*)(obuf + (size_t)row1 * kH + col);
    v.x += w.x; v.y += w.y; v.z += w.z; v.w += w.w;
  }
  *(float4*)(out + (size_t)t * kH + col) = v;
}

// ---------------- launcher ----------------
extern "C" void kernel_launch(void* const* d_in, const int* in_sizes, int n_in,
                              void* d_out, int out_size, void* d_ws, size_t ws_size,
                              hipStream_t stream) {
  const float* hs   = (const float*)d_in[0];
  const float* aff  = (const float*)d_in[1];
  const int*   eidx = (const int*)d_in[2];
  const float* wg   = (const float*)d_in[3];
  const float* wu   = (const float*)d_in[4];
  const float* wd   = (const float*)d_in[5];
  float* out = (float*)d_out;

  char* ws = (char*)d_ws;
  unsigned short* hsb  = (unsigned short*)(ws + HSB_OFF);
  unsigned short* hbuf = (unsigned short*)(ws + HBUF_OFF);
  unsigned short* wgT  = (unsigned short*)(ws + RA_OFF);   // later: wdT
  unsigned short* wdT  = (unsigned short*)(ws + RA_OFF);
  unsigned short* wuT  = (unsigned short*)(ws + RB_OFF);   // later: obuf
  float*          obuf = (float*)(ws + RB_OFF);
  int*            cnts = (int*)(ws + CNT_OFF);
  int*            offs = (int*)(ws + OFF_OFF);
  int*            ltok = (int*)(ws + LTOK_OFF);
  float*          lwgt = (float*)(ws + LW_OFF);
  int*            pos  = (int*)(ws + POS_OFF);
  float*          wrow = (float*)(ws + WROW_OFF);

  hipMemsetAsync(cnts, 0, kE * sizeof(int), stream);

  cvt_hs_kernel<<<(kT * kH) / (256 * 8), 256, 0, stream>>>(hs, hsb);
  route_kernel<<<kT / 256, 256, 0, stream>>>(aff, eidx, cnts, ltok, lwgt, pos);
  prefix_kernel<<<1, 64, 0, stream>>>(cnts, offs);
  wrow_kernel<<<(kE * kCap) / 256, 256, 0, stream>>>(cnts, offs, lwgt, wrow);

  tcvt_kernel<<<dim3(kI / 64, kH / 64, kE), 256, 0, stream>>>(wg, wgT, kH, kI);
  tcvt_kernel<<<dim3(kI / 64, kH / 64, kE), 256, 0, stream>>>(wu, wuT, kH, kI);

  gemm_gu_kernel<<<dim3(kI / 128, kCap / 256, kE), 512, 0, stream>>>(
      hsb, wgT, wuT, cnts, offs, ltok, wrow, hbuf);

  tcvt_kernel<<<dim3(kH / 64, kI / 64, kE), 256, 0, stream>>>(wd, wdT, kI, kH);

  gemm_dn_kernel<<<dim3(kH / 256, kCap / 256, kE), 512, 0, stream>>>(
      hbuf, wdT, cnts, offs, obuf);

  combine_kernel<<<dim3(kH / 1024, kT), 256, 0, stream>>>(obuf, pos, offs, out);
}

// Round 12
// 754.834 us; speedup vs baseline: 1.0279x; 1.0266x over previous
//
#include <hip/hip_runtime.h>
#include <hip/hip_bf16.h>

// ExpertMLPsV2: T=4096, H=2048, I=4096, E=8, TOPK=2.
// cvt/route -> tcvt weights bf16 (N,K) -> fused gate+up GEMM (8-phase m201-style
// schedule) -> tcvt wd -> down GEMM (same) -> combine.
// GEMM schedule (per 64-K tile, dbuf 2x64KB, 4 phases):
//   ph = { ds-reads ; stage 1 half-tile (2 gload_lds) ; BAR ; 16-MFMA setprio ; BAR }
// Stage lags reads by one phase; vmcnt(6) once per tile at ph4 (3 half-tiles in
// flight). Rows are 128B -> 8-slot XOR swizzle slot^(row&7), staged via
// pre-swizzled global source (linear LDS dest), read XOR folds per-lane.

constexpr int kT   = 4096;
constexpr int kH   = 2048;
constexpr int kI   = 4096;
constexpr int kE   = 8;
constexpr int kCap = 4096;
constexpr int kRowsCap = 10240;

typedef __attribute__((ext_vector_type(8))) short bf16x8;
typedef __attribute__((ext_vector_type(4))) float f32x4;

// ---------------- workspace layout ----------------
constexpr size_t HSB_OFF  = 0;                                      // hs bf16 16 MiB
constexpr size_t HBUF_OFF = 16777216;                               // h bf16 rowsCap x kI (80 MiB)
constexpr size_t RA_OFF   = HBUF_OFF + (size_t)kRowsCap * kI * 2;   // wgT -> wdT (128 MiB)
constexpr size_t RB_OFF   = RA_OFF + (size_t)kE * kH * kI * 2;      // wuT -> obuf (128 MiB)
constexpr size_t CNT_OFF  = RB_OFF + (size_t)kE * kH * kI * 2;
constexpr size_t OFF_OFF  = CNT_OFF + 256;
constexpr size_t LTOK_OFF = OFF_OFF + 256;
constexpr size_t LW_OFF   = LTOK_OFF + (size_t)kE * kCap * 4;
constexpr size_t POS_OFF  = LW_OFF + (size_t)kE * kCap * 4;
constexpr size_t WROW_OFF = POS_OFF + (size_t)kT * 2 * 4;
// end ~373 MiB

__device__ __forceinline__ unsigned short f2bf(float x) {   // RNE f32->bf16
  unsigned int u = __float_as_uint(x);
  u += 0x7FFFu + ((u >> 16) & 1u);
  return (unsigned short)(u >> 16);
}
__device__ __forceinline__ unsigned pk2(float a, float b) {
  return (unsigned)f2bf(a) | ((unsigned)f2bf(b) << 16);
}
__device__ __forceinline__ float silu_f(float x) { return x / (1.f + __expf(-x)); }

__device__ __forceinline__ void async_copy16(void* lds, const void* g) {
  __builtin_amdgcn_global_load_lds(
      (const __attribute__((address_space(1))) void*)g,
      (__attribute__((address_space(3))) void*)lds, 16, 0, 0);
}

#define MFMA_BF16 __builtin_amdgcn_mfma_f32_16x16x32_bf16

// ---------------- kernel 1: fp32 -> bf16 hidden states ----------------
__global__ void cvt_hs_kernel(const float* __restrict__ in, unsigned short* __restrict__ out) {
  size_t i = ((size_t)blockIdx.x * 256 + threadIdx.x) * 8;
  float4 a = *(const float4*)(in + i);
  float4 b = *(const float4*)(in + i + 4);
  uint4 v;
  v.x = pk2(a.x, a.y); v.y = pk2(a.z, a.w);
  v.z = pk2(b.x, b.y); v.w = pk2(b.z, b.w);
  *(uint4*)(out + i) = v;
}

// ---------------- kernel 1b: transpose+convert (K,N) f32 -> (N,K) bf16 -------
__global__ __launch_bounds__(256)
void tcvt_kernel(const float* __restrict__ src, unsigned short* __restrict__ dst,
                 int K, int N) {
  __shared__ __attribute__((aligned(16))) unsigned short s[64][72];
  const size_t mat = (size_t)K * N;
  const float* S = src + (size_t)blockIdx.z * mat;
  unsigned short* D = dst + (size_t)blockIdx.z * mat;
  const int k0 = blockIdx.y * 64, n0 = blockIdx.x * 64;
  const int t  = threadIdx.x;
  const int n4 = (t & 15) * 4;
  const int k4 = (t >> 4) * 4;
  const float* p0 = S + (size_t)(k0 + k4) * N + n0 + n4;
  float4 r0 = *(const float4*)(p0);
  float4 r1 = *(const float4*)(p0 + N);
  float4 r2 = *(const float4*)(p0 + 2 * (size_t)N);
  float4 r3 = *(const float4*)(p0 + 3 * (size_t)N);
  uint2 v;
  v.x = pk2(r0.x, r1.x); v.y = pk2(r2.x, r3.x); *(uint2*)(&s[n4 + 0][k4]) = v;
  v.x = pk2(r0.y, r1.y); v.y = pk2(r2.y, r3.y); *(uint2*)(&s[n4 + 1][k4]) = v;
  v.x = pk2(r0.z, r1.z); v.y = pk2(r2.z, r3.z); *(uint2*)(&s[n4 + 2][k4]) = v;
  v.x = pk2(r0.w, r1.w); v.y = pk2(r2.w, r3.w); *(uint2*)(&s[n4 + 3][k4]) = v;
  __syncthreads();
  const int nn = t >> 3;
  const int kc = (t & 7) * 8;
#pragma unroll
  for (int i = 0; i < 2; ++i) {
    const int n = nn + i * 32;
    uint4 u = *(const uint4*)(&s[n][kc]);
    *(uint4*)(D + (size_t)(n0 + n) * K + k0 + kc) = u;
  }
}

// ---------------- kernel 2: routing ----------------
__global__ void route_kernel(const float* __restrict__ aff, const int* __restrict__ idx,
                             int* counts, int* ltok, float* lw, int* pos) {
  int t = blockIdx.x * 256 + threadIdx.x;
  if (t >= kT) return;
  int e0 = idx[t * 2 + 0];
  int e1 = idx[t * 2 + 1];
  float a0 = aff[t * kE + e0];
  float a1 = aff[t * kE + e1];
  if (e0 == e1) {
    float w = a0 / fmaxf(fabsf(a0), 1e-12f);
    int s = atomicAdd(&counts[e0], 1);
    ltok[e0 * kCap + s] = t;
    lw[e0 * kCap + s]   = w;
    pos[t * 2 + 0] = (e0 << 12) | s;
    pos[t * 2 + 1] = -1;
  } else {
    float d = fmaxf(fabsf(a0) + fabsf(a1), 1e-12f);
    int s0 = atomicAdd(&counts[e0], 1);
    ltok[e0 * kCap + s0] = t;
    lw[e0 * kCap + s0]   = a0 / d;
    int s1 = atomicAdd(&counts[e1], 1);
    ltok[e1 * kCap + s1] = t;
    lw[e1 * kCap + s1]   = a1 / d;
    pos[t * 2 + 0] = (e0 << 12) | s0;
    pos[t * 2 + 1] = (e1 << 12) | s1;
  }
}

// 256-aligned prefix offsets
__global__ void prefix_kernel(const int* __restrict__ counts, int* offs) {
  if (threadIdx.x == 0 && blockIdx.x == 0) {
    int acc = 0;
    for (int e = 0; e < kE; ++e) { offs[e] = acc; acc += (counts[e] + 255) & ~255; }
  }
}

// per-slot-row affinity weight (0 for align-pad rows)
__global__ void wrow_kernel(const int* __restrict__ counts, const int* __restrict__ offs,
                            const float* __restrict__ lw, float* __restrict__ wrow) {
  int idx = blockIdx.x * 256 + threadIdx.x;
  int e = idx >> 12, s = idx & 4095;
  int cnt = counts[e];
  int al  = (cnt + 255) & ~255;
  if (s < al) wrow[offs[e] + s] = (s < cnt) ? lw[e * kCap + s] : 0.f;
}

// ---------------- kernel 3: fused gate+up GEMM, 8-phase schedule -------------
// BM=256, BN=128(x2 mats), BK=64. 8 waves (2 m-groups x 4 n-panels); per-wave
// output: (2 m-halves x 64m) x 32n per matrix -> accG/accU [8][2].
// LDS buffer (64 KiB): A [256][64] @0 (halves @0/@16384), Wg @32768, Wu @49152.
// grid (kI/128, kCap/256, E), 512 threads.
__global__ __launch_bounds__(512, 2)
void gemm_gu_kernel(const unsigned short* __restrict__ hsb,
                    const unsigned short* __restrict__ wgT,   // (E, I, H) bf16
                    const unsigned short* __restrict__ wuT,
                    const int* __restrict__ counts, const int* __restrict__ offs,
                    const int* __restrict__ ltok, const float* __restrict__ wrow,
                    unsigned short* __restrict__ hbuf) {
  constexpr int NT = kH / 64;   // 32 K-tiles
  __shared__ __attribute__((aligned(16))) unsigned short lds[2 * 32768];

  const int e   = blockIdx.z;
  const int cnt = counts[e];
  const int m0  = blockIdx.y * 256;
  if (m0 >= cnt) return;
  const int n0   = blockIdx.x * 128;
  const int tid  = threadIdx.x;
  const int lane = tid & 63;
  const int wv   = tid >> 6;
  const int wm   = wv >> 2;        // m-group (64 rows in each 128-half)
  const int wn   = wv & 3;         // n-panel of 32
  const int baseRow = offs[e] + m0;

  // staging: half-tile = 128 rows x 64k = 1024 16B chunks; thread handles
  // c=tid (rows 0-63) and c=tid+512 (rows 64-127). Physical slot tid&7 holds
  // logical slot (tid&7)^((tid>>3)&7) [8-slot involution per 128B row].
  const int skof = ((tid & 7) ^ ((tid >> 3) & 7)) * 8;
  const int r_   = tid >> 3;
  int s0 = m0 + r_;        s0 = s0 < cnt ? s0 : cnt - 1;
  int s1 = m0 + 64 + r_;   s1 = s1 < cnt ? s1 : cnt - 1;
  int s2 = m0 + 128 + r_;  s2 = s2 < cnt ? s2 : cnt - 1;
  int s3 = m0 + 192 + r_;  s3 = s3 < cnt ? s3 : cnt - 1;
  const unsigned short* aP0 = hsb + (size_t)ltok[e * kCap + s0] * kH + skof;
  const unsigned short* aP1 = hsb + (size_t)ltok[e * kCap + s1] * kH + skof;
  const unsigned short* aP2 = hsb + (size_t)ltok[e * kCap + s2] * kH + skof;
  const unsigned short* aP3 = hsb + (size_t)ltok[e * kCap + s3] * kH + skof;
  const unsigned short* wgP0 = wgT + (size_t)e * kI * kH + (size_t)(n0 + r_) * kH + skof;
  const unsigned short* wgP1 = wgT + (size_t)e * kI * kH + (size_t)(n0 + 64 + r_) * kH + skof;
  const unsigned short* wuP0 = wuT + (size_t)e * kI * kH + (size_t)(n0 + r_) * kH + skof;
  const unsigned short* wuP1 = wuT + (size_t)e * kI * kH + (size_t)(n0 + 64 + r_) * kH + skof;

  char* ldsb = (char*)lds;
  const int stO0 = tid * 16;
  const int stO1 = tid * 16 + 8192;
  const int ar  = lane & 15;
  const int lg  = lane >> 4;
  const int sk0 = ((lg ^ (lane & 7)) << 4);          // k=0 slot, swizzle folded
  const int sk1 = (((4 + lg) ^ (lane & 7)) << 4);    // k=1 slot

  f32x4 accG[8][2] = {};
  f32x4 accU[8][2] = {};
  bf16x8 a0[4][2], a1[4][2], wgf[2][2], wuf[2][2];

#define STG2(dst, p0, p1, tt) {                                   \
    async_copy16((dst) + stO0, (p0) + (size_t)(tt) * 64);         \
    async_copy16((dst) + stO1, (p1) + (size_t)(tt) * 64); }
#define RD_A(dst, base, mh) _Pragma("unroll")                                  \
  for (int mf = 0; mf < 4; ++mf) {                                             \
    const char* rp_ = (base) + ((mh) * 128 + wm * 64 + mf * 16 + ar) * 128;    \
    dst[mf][0] = *(const bf16x8*)(rp_ + sk0);                                  \
    dst[mf][1] = *(const bf16x8*)(rp_ + sk1); }
#define RD_W(dst, base) _Pragma("unroll")                                      \
  for (int nf = 0; nf < 2; ++nf) {                                             \
    const char* rp_ = (base) + (wn * 32 + nf * 16 + ar) * 128;                 \
    dst[nf][0] = *(const bf16x8*)(rp_ + sk0);                                  \
    dst[nf][1] = *(const bf16x8*)(rp_ + sk1); }
#define MMA16(ACC, W, A, MH)                                                   \
  __builtin_amdgcn_s_setprio(1);                                               \
  _Pragma("unroll") for (int mf = 0; mf < 4; ++mf)                             \
    _Pragma("unroll") for (int nf = 0; nf < 2; ++nf) {                         \
      ACC[(MH)*4+mf][nf] = MFMA_BF16(W[nf][0], A[mf][0], ACC[(MH)*4+mf][nf], 0, 0, 0); \
      ACC[(MH)*4+mf][nf] = MFMA_BF16(W[nf][1], A[mf][1], ACC[(MH)*4+mf][nf], 0, 0, 0); \
    }                                                                          \
  __builtin_amdgcn_s_setprio(0);

  // GU tile t: buffers bc=t&1 (compute), bo=(t+1)&1.
  // ph1: rd A0,Wg | stage A1(t+1)->bo ; MMA G(mh0)
  // ph2: rd Wu    | stage A0(t+2)->bc ; MMA U(mh0)
  // ph3: rd A1    | stage Wg(t+2)->bc ; MMA G(mh1)
  // ph4:          | stage Wu(t+2)->bc ; MMA U(mh1) ; vmcnt ; BAR
#define GU_TILE(t, SA1, SM, VM)                                                \
  {                                                                            \
    char* bc = ldsb + ((t) & 1) * 65536;                                       \
    char* bo = ldsb + (((t) + 1) & 1) * 65536;                                 \
    RD_A(a0, bc, 0); RD_W(wgf, bc + 32768);                                    \
    if (SA1) STG2(bo + 16384, aP2, aP3, (t) + 1);                              \
    __builtin_amdgcn_s_barrier();                                              \
    MMA16(accG, wgf, a0, 0);                                                   \
    __builtin_amdgcn_s_barrier();                                              \
    RD_W(wuf, bc + 49152);                                                     \
    if (SM) STG2(bc, aP0, aP1, (t) + 2);                                       \
    __builtin_amdgcn_s_barrier();                                              \
    MMA16(accU, wuf, a0, 0);                                                   \
    __builtin_amdgcn_s_barrier();                                              \
    RD_A(a1, bc, 1);                                                           \
    if (SM) STG2(bc + 32768, wgP0, wgP1, (t) + 2);                             \
    __builtin_amdgcn_s_barrier();                                              \
    MMA16(accG, wgf, a1, 1);                                                   \
    __builtin_amdgcn_s_barrier();                                              \
    if (SM) STG2(bc + 49152, wuP0, wuP1, (t) + 2);                             \
    __builtin_amdgcn_s_barrier();                                              \
    MMA16(accU, wuf, a1, 1);                                                   \
    if ((VM) >= 0) {                                                           \
      asm volatile("s_waitcnt vmcnt(%0)" :: "i"((VM) < 0 ? 0 : (VM)) : "memory"); \
      __builtin_amdgcn_s_barrier();                                            \
    }                                                                          \
  }

  // prologue: tile0 complete + tile1's A0/Wg/Wu (A1(1) staged at t0.ph1)
  {
    char* b0 = ldsb;
    char* b1 = ldsb + 65536;
    STG2(b0,         aP0, aP1, 0);
    STG2(b0 + 16384, aP2, aP3, 0);
    STG2(b0 + 32768, wgP0, wgP1, 0);
    STG2(b0 + 49152, wuP0, wuP1, 0);
    STG2(b1,         aP0, aP1, 1);
    STG2(b1 + 32768, wgP0, wgP1, 1);
    STG2(b1 + 49152, wuP0, wuP1, 1);
    asm volatile("s_waitcnt vmcnt(6)" ::: "memory");
    __builtin_amdgcn_s_barrier();
  }

  for (int t = 0; t < NT - 2; ++t) GU_TILE(t, 1, 1, 6);
  GU_TILE(NT - 2, 1, 0, 0);
  GU_TILE(NT - 1, 0, 0, -1);
#undef GU_TILE

  // epilogue: h = silu(g)*u*wrow -> bf16 hbuf
  const int lr4 = lg * 4;
#pragma unroll
  for (int mh = 0; mh < 2; ++mh)
#pragma unroll
    for (int mf = 0; mf < 4; ++mf) {
      const int grow = baseRow + mh * 128 + wm * 64 + mf * 16 + ar;
      const float wf = wrow[grow];
#pragma unroll
      for (int nf = 0; nf < 2; ++nf) {
        const int n = n0 + wn * 32 + nf * 16 + lr4;
        f32x4 g = accG[mh * 4 + mf][nf], u = accU[mh * 4 + mf][nf];
        float h0 = silu_f(g[0]) * u[0] * wf;
        float h1 = silu_f(g[1]) * u[1] * wf;
        float h2 = silu_f(g[2]) * u[2] * wf;
        float h3 = silu_f(g[3]) * u[3] * wf;
        uint2 v;
        v.x = pk2(h0, h1);
        v.y = pk2(h2, h3);
        *(uint2*)(hbuf + ((size_t)grow * kI + n)) = v;
      }
    }
#undef STG2
#undef RD_A
#undef RD_W
#undef MMA16
}

// ---------------- kernel 4: down GEMM, 8-phase schedule ----------------
// BM=256, BN=256, BK=64. 8 waves; per-wave (2 mh x 64m) x (2 nh x 32n) ->
// acc[8][4]. LDS buffer (64 KiB): A @0 (halves 0/16384), W @32768 (halves
// 32768/49152). grid (kH/256, kCap/256, E), 512 threads.
__global__ __launch_bounds__(512, 2)
void gemm_dn_kernel(const unsigned short* __restrict__ hbuf,
                    const unsigned short* __restrict__ wdT,   // (E, H, I) bf16
                    const int* __restrict__ counts, const int* __restrict__ offs,
                    float* __restrict__ obuf) {
  constexpr int NT = kI / 64;   // 64 K-tiles
  __shared__ __attribute__((aligned(16))) unsigned short lds[2 * 32768];

  const int e   = blockIdx.z;
  const int cnt = counts[e];
  const int m0  = blockIdx.y * 256;
  if (m0 >= cnt) return;
  const int n0   = blockIdx.x * 256;
  const int tid  = threadIdx.x;
  const int lane = tid & 63;
  const int wv   = tid >> 6;
  const int wm   = wv >> 2;
  const int wn   = wv & 3;
  const int baseRow = offs[e] + m0;

  const int skof = ((tid & 7) ^ ((tid >> 3) & 7)) * 8;
  const int r_   = tid >> 3;
  const unsigned short* aP0 = hbuf + (size_t)(baseRow + r_) * kI + skof;
  const unsigned short* aP1 = hbuf + (size_t)(baseRow + 64 + r_) * kI + skof;
  const unsigned short* aP2 = hbuf + (size_t)(baseRow + 128 + r_) * kI + skof;
  const unsigned short* aP3 = hbuf + (size_t)(baseRow + 192 + r_) * kI + skof;
  const unsigned short* wB = wdT + (size_t)e * kH * kI;
  const unsigned short* wP0 = wB + (size_t)(n0 + r_) * kI + skof;
  const unsigned short* wP1 = wB + (size_t)(n0 + 64 + r_) * kI + skof;
  const unsigned short* wP2 = wB + (size_t)(n0 + 128 + r_) * kI + skof;
  const unsigned short* wP3 = wB + (size_t)(n0 + 192 + r_) * kI + skof;

  char* ldsb = (char*)lds;
  const int stO0 = tid * 16;
  const int stO1 = tid * 16 + 8192;
  const int ar  = lane & 15;
  const int lg  = lane >> 4;
  const int sk0 = ((lg ^ (lane & 7)) << 4);
  const int sk1 = (((4 + lg) ^ (lane & 7)) << 4);

  f32x4 acc[8][4] = {};
  bf16x8 a0[4][2], a1[4][2], w0[2][2], w1[2][2];

#define STG2(dst, p0, p1, tt) {                                   \
    async_copy16((dst) + stO0, (p0) + (size_t)(tt) * 64);         \
    async_copy16((dst) + stO1, (p1) + (size_t)(tt) * 64); }
#define RD_A(dst, base, mh) _Pragma("unroll")                                  \
  for (int mf = 0; mf < 4; ++mf) {                                             \
    const char* rp_ = (base) + ((mh) * 128 + wm * 64 + mf * 16 + ar) * 128;    \
    dst[mf][0] = *(const bf16x8*)(rp_ + sk0);                                  \
    dst[mf][1] = *(const bf16x8*)(rp_ + sk1); }
#define RD_WN(dst, base, nh) _Pragma("unroll")                                 \
  for (int nf = 0; nf < 2; ++nf) {                                             \
    const char* rp_ = (base) + ((nh) * 128 + wn * 32 + nf * 16 + ar) * 128;    \
    dst[nf][0] = *(const bf16x8*)(rp_ + sk0);                                  \
    dst[nf][1] = *(const bf16x8*)(rp_ + sk1); }
#define MMA16(W, A, MH, NH)                                                    \
  __builtin_amdgcn_s_setprio(1);                                               \
  _Pragma("unroll") for (int mf = 0; mf < 4; ++mf)                             \
    _Pragma("unroll") for (int nf = 0; nf < 2; ++nf) {                         \
      acc[(MH)*4+mf][(NH)*2+nf] = MFMA_BF16(W[nf][0], A[mf][0], acc[(MH)*4+mf][(NH)*2+nf], 0, 0, 0); \
      acc[(MH)*4+mf][(NH)*2+nf] = MFMA_BF16(W[nf][1], A[mf][1], acc[(MH)*4+mf][(NH)*2+nf], 0, 0, 0); \
    }                                                                          \
  __builtin_amdgcn_s_setprio(0);

#define DN_TILE(t, SA1, SM, VM)                                                \
  {                                                                            \
    char* bc = ldsb + ((t) & 1) * 65536;                                       \
    char* bo = ldsb + (((t) + 1) & 1) * 65536;                                 \
    RD_A(a0, bc, 0); RD_WN(w0, bc + 32768, 0);                                 \
    if (SA1) STG2(bo + 16384, aP2, aP3, (t) + 1);                              \
    __builtin_amdgcn_s_barrier();                                              \
    MMA16(w0, a0, 0, 0);                                                       \
    __builtin_amdgcn_s_barrier();                                              \
    RD_WN(w1, bc + 32768, 1);                                                  \
    if (SM) STG2(bc, aP0, aP1, (t) + 2);                                       \
    __builtin_amdgcn_s_barrier();                                              \
    MMA16(w1, a0, 0, 1);                                                       \
    __builtin_amdgcn_s_barrier();                                              \
    RD_A(a1, bc, 1);                                                           \
    if (SM) STG2(bc + 32768, wP0, wP1, (t) + 2);                               \
    __builtin_amdgcn_s_barrier();                                              \
    MMA16(w0, a1, 1, 0);                                                       \
    __builtin_amdgcn_s_barrier();                                              \
    if (SM) STG2(bc + 49152, wP2, wP3, (t) + 2);                               \
    __builtin_amdgcn_s_barrier();                                              \
    MMA16(w1, a1, 1, 1);                                                       \
    if ((VM) >= 0) {                                                           \
      asm volatile("s_waitcnt vmcnt(%0)" :: "i"((VM) < 0 ? 0 : (VM)) : "memory"); \
      __builtin_amdgcn_s_barrier();                                            \
    }                                                                          \
  }

  {
    char* b0 = ldsb;
    char* b1 = ldsb + 65536;
    STG2(b0,         aP0, aP1, 0);
    STG2(b0 + 16384, aP2, aP3, 0);
    STG2(b0 + 32768, wP0, wP1, 0);
    STG2(b0 + 49152, wP2, wP3, 0);
    STG2(b1,         aP0, aP1, 1);
    STG2(b1 + 32768, wP0, wP1, 1);
    STG2(b1 + 49152, wP2, wP3, 1);
    asm volatile("s_waitcnt vmcnt(6)" ::: "memory");
    __builtin_amdgcn_s_barrier();
  }

  for (int t = 0; t < NT - 2; ++t) DN_TILE(t, 1, 1, 6);
  DN_TILE(NT - 2, 1, 0, 0);
  DN_TILE(NT - 1, 0, 0, -1);
#undef DN_TILE

  const int lr4 = lg * 4;
#pragma unroll
  for (int mh = 0; mh < 2; ++mh)
#pragma unroll
    for (int mf = 0; mf < 4; ++mf) {
      const int grow = baseRow + mh * 128 + wm * 64 + mf * 16 + ar;
#pragma unroll
      for (int nh = 0; nh < 2; ++nh)
#pragma unroll
        for (int nf = 0; nf < 2; ++nf) {
          const int n = n0 + nh * 128 + wn * 32 + nf * 16 + lr4;
          *(f32x4*)(obuf + (size_t)grow * kH + n) = acc[mh * 4 + mf][nh * 2 + nf];
        }
    }
#undef STG2
#undef RD_A
#undef RD_WN
#undef MMA16
}

// ---------------- kernel 5: combine obuf slots -> out ----------------
__global__ void combine_kernel(const float* __restrict__ obuf,
                               const int* __restrict__ pos,
                               const int* __restrict__ offs,
                               float* __restrict__ out) {
  const int t   = blockIdx.y;
  const int col = blockIdx.x * 1024 + threadIdx.x * 4;
  const int c0  = pos[t * 2 + 0];
  const int c1  = pos[t * 2 + 1];
  const int row0 = offs[c0 >> 12] + (c0 & 4095);
  float4 v = *(const float4*)(obuf + (size_t)row0 * kH + col);
  if (c1 >= 0) {
    const int row1 = offs[c1 >> 12] + (c1 & 4095);
    float4 w = *(const float4*)(obuf + (size_t)row1 * kH + col);
    v.x += w.x; v.y += w.y; v.z += w.z; v.w += w.w;
  }
  *(float4*)(out + (size_t)t * kH + col) = v;
}

// ---------------- launcher ----------------
extern "C" void kernel_launch(void* const* d_in, const int* in_sizes, int n_in,
                              void* d_out, int out_size, void* d_ws, size_t ws_size,
                              hipStream_t stream) {
  const float* hs   = (const float*)d_in[0];
  const float* aff  = (const float*)d_in[1];
  const int*   eidx = (const int*)d_in[2];
  const float* wg   = (const float*)d_in[3];
  const float* wu   = (const float*)d_in[4];
  const float* wd   = (const float*)d_in[5];
  float* out = (float*)d_out;

  char* ws = (char*)d_ws;
  unsigned short* hsb  = (unsigned short*)(ws + HSB_OFF);
  unsigned short* hbuf = (unsigned short*)(ws + HBUF_OFF);
  unsigned short* wgT  = (unsigned short*)(ws + RA_OFF);   // later: wdT
  unsigned short* wdT  = (unsigned short*)(ws + RA_OFF);
  unsigned short* wuT  = (unsigned short*)(ws + RB_OFF);   // later: obuf
  float*          obuf = (float*)(ws + RB_OFF);
  int*            cnts = (int*)(ws + CNT_OFF);
  int*            offs = (int*)(ws + OFF_OFF);
  int*            ltok = (int*)(ws + LTOK_OFF);
  float*          lwgt = (float*)(ws + LW_OFF);
  int*            pos  = (int*)(ws + POS_OFF);
  float*          wrow = (float*)(ws + WROW_OFF);

  hipMemsetAsync(cnts, 0, kE * sizeof(int), stream);

  cvt_hs_kernel<<<(kT * kH) / (256 * 8), 256, 0, stream>>>(hs, hsb);
  route_kernel<<<kT / 256, 256, 0, stream>>>(aff, eidx, cnts, ltok, lwgt, pos);
  prefix_kernel<<<1, 64, 0, stream>>>(cnts, offs);
  wrow_kernel<<<(kE * kCap) / 256, 256, 0, stream>>>(cnts, offs, lwgt, wrow);

  tcvt_kernel<<<dim3(kI / 64, kH / 64, kE), 256, 0, stream>>>(wg, wgT, kH, kI);
  tcvt_kernel<<<dim3(kI / 64, kH / 64, kE), 256, 0, stream>>>(wu, wuT, kH, kI);

  gemm_gu_kernel<<<dim3(kI / 128, kCap / 256, kE), 512, 0, stream>>>(
      hsb, wgT, wuT, cnts, offs, ltok, wrow, hbuf);

  tcvt_kernel<<<dim3(kH / 64, kI / 64, kE), 256, 0, stream>>>(wd, wdT, kI, kH);

  gemm_dn_kernel<<<dim3(kH / 256, kCap / 256, kE), 512, 0, stream>>>(
      hbuf, wdT, cnts, offs, obuf);

  combine_kernel<<<dim3(kH / 1024, kT), 256, 0, stream>>>(obuf, pos, offs, out);
}